// Round 8
// baseline (503.463 us; speedup 1.0000x reference)
//
#include <hip/hip_runtime.h>
#include <hip/hip_bf16.h>
#include <stdint.h>

typedef unsigned short u16;
typedef __attribute__((ext_vector_type(8))) short short8;
typedef __attribute__((ext_vector_type(8))) u16   u16x8;
typedef __attribute__((ext_vector_type(4))) u16   u16x4;
typedef __attribute__((ext_vector_type(4))) float f32x4;

#define B_DIM  8192
#define G_DIM  20000
#define H1_DIM 512
#define H2_DIM 256
#define P_DIM  128
#define A_DIM  64
#define SPLITK 8

union Frag { short8 s; u16x8 u; };

__device__ __forceinline__ u16 f2b(float f) {
  union { __hip_bfloat16 b; u16 u; } c;
  c.b = __float2bfloat16(f);
  return c.u;
}

__device__ __forceinline__ void gld16(const void* g, void* l) {
  __builtin_amdgcn_global_load_lds(
      (const __attribute__((address_space(1))) void*)g,
      (__attribute__((address_space(3))) void*)l, 16, 0, 0);
}

// ---------------- prep: f32 -> bf16 convert (vectorized) ----------------
__global__ void k_convert(const float* __restrict__ src, u16* __restrict__ dst, int n4) {
  int i = blockIdx.x * 256 + threadIdx.x;
  if (i >= n4) return;
  f32x4 v = ((const f32x4*)src)[i];
  u16x4 o;
  o[0] = f2b(v[0]); o[1] = f2b(v[1]);
  o[2] = f2b(v[2]); o[3] = f2b(v[3]);
  ((u16x4*)dst)[i] = o;
}

// ---------------- prep: W3[p][h][a] f32 -> W3T[p][a][h] bf16 ----------------
__global__ void k_transpose_w3(const float* __restrict__ W3, u16* __restrict__ W3T) {
  int idx = blockIdx.x * 256 + threadIdx.x;     // = (p*64+a)*256 + h
  if (idx >= P_DIM * H2_DIM * A_DIM) return;
  int h = idx & (H2_DIM - 1);
  int a = (idx >> 8) & (A_DIM - 1);
  int p = idx >> 14;
  W3T[idx] = f2b(W3[((size_t)p * H2_DIM + h) * A_DIM + a]);
}

// ---------------- K1: layer-1 GEMM (HBM-bound: stream X once) ----------------
// BM=64, BN=512 (full H1), BK=32, SPLITK=8 via ks=blockIdx&7 (XCD-uniform
// K-slice -> W1b slice L2-resident; R7-verified: FETCH ~= X only).
// R8 change: A reg-prefetched 2 iters ahead + raw s_barrier with counted
// vmcnt(1) so the A(t+2) HBM load (~900cyc) crosses the barrier un-drained.
// B double-buffered via gld16 staged 1 ahead (L2-warm, compute-section cover).
// Barrier invariant: outstanding = {B(t+1)x4, A(t+2)} -> vmcnt(1).
__global__ __launch_bounds__(512, 4)   // 4 waves/EU -> 2 blocks/CU, 128 VGPR cap
void k_gemm1(const float* __restrict__ X, const u16* __restrict__ W1b,
             float* __restrict__ partial) {
  const int ks = blockIdx.x & 7;
  const int m0 = (blockIdx.x >> 3) * 64;
  const int kt_begin = (ks == 0) ? 0 : (ks * 78 + 1);   // {79, 78x7} of 625
  const int nkt = (ks == 0) ? 79 : 78;

  const int tid  = threadIdx.x;
  const int lane = tid & 63;
  const int w    = tid >> 6;            // wave 0..7 -> N rows w*64..
  const int c15 = lane & 15, j4 = lane >> 4;

  __shared__ u16 lsA[2][64 * 32];       // 4 KB/buf; row = 64B = 4 slots x 16B, swz slot^((row>>1)&3)
  __shared__ u16 lsB[2][512 * 32];      // 32 KB/buf; same row layout

  // A staging: thread -> row tid>>3 (0..63), granule tid&7 (16B f32 load -> 8B LDS write)
  const int aRow = tid >> 3;
  const int aG   = tid & 7;
  const int aPhysU16 = aRow * 32 + (((aG >> 1) ^ ((aRow >> 1) & 3)) << 3) + ((aG & 1) << 2);
  const float* aSrc0 = X + (size_t)(m0 + aRow) * G_DIM + aG * 4;

  f32x4 zero = {0.f, 0.f, 0.f, 0.f};
  f32x4 acc[4][4];
#pragma unroll
  for (int m = 0; m < 4; ++m)
#pragma unroll
    for (int n = 0; n < 4; ++n) acc[m][n] = zero;

  auto ktc = [&](int t) { return kt_begin + (t < nkt ? t : nkt - 1); };

  auto stageB = [&](int buf, int kt) {
    const int k0 = kt * 32;
#pragma unroll
    for (int c = 0; c < 4; ++c) {
      int lin = c * 512 + tid;
      int row = lin >> 2, slot = lin & 3;
      int gslot = slot ^ ((row >> 1) & 3);
      gld16(W1b + (size_t)row * G_DIM + k0 + gslot * 8, &lsB[buf][lin * 8]);
    }
  };
  auto loadA = [&](int kt, f32x4& ar) {
    ar = *(const f32x4*)(aSrc0 + (size_t)kt * 32);
  };
  auto writeA = [&](int buf, const f32x4& ar) {
    u16x4 o;
    o[0] = f2b(ar[0]); o[1] = f2b(ar[1]); o[2] = f2b(ar[2]); o[3] = f2b(ar[3]);
    *(u16x4*)&lsA[buf][aPhysU16] = o;
  };

  f32x4 arE, arO;   // 2-deep A pipeline (even/odd)

  // ---- prologue: B0 staged; A0,A1 in flight; A0 -> LDS ----
  stageB(0, ktc(0));                    // B0 x4 (oldest)
  asm volatile("" ::: "memory");
  loadA(ktc(0), arE);                   // A0
  asm volatile("" ::: "memory");
  loadA(ktc(1), arO);                   // A1
  asm volatile("" ::: "memory");
  writeA(0, arE);                       // compiler waits A0 (vmcnt(1)) -> retires B0 too
  asm volatile("s_waitcnt vmcnt(1) lgkmcnt(0)" ::: "memory");  // keep A1 in flight
  __builtin_amdgcn_s_barrier();
  __builtin_amdgcn_sched_barrier(0);

  auto body = [&](int t, int buf, f32x4& arLoad, const f32x4& arWrite) {
    stageB(buf ^ 1, ktc(t + 1));        // 4 gld16 into buffer freed at last barrier
    asm volatile("" ::: "memory");
    loadA(ktc(t + 2), arLoad);          // A(t+2): crosses next barrier in flight
    asm volatile("" ::: "memory");

    Frag afr[4], bfr[4];
#pragma unroll
    for (int m = 0; m < 4; ++m) {
      int row = m * 16 + c15;
      int phys = j4 ^ ((row >> 1) & 3);
      afr[m].s = *(const short8*)&lsA[buf][row * 32 + phys * 8];
    }
#pragma unroll
    for (int n = 0; n < 4; ++n) {
      int row = w * 64 + n * 16 + c15;
      int phys = j4 ^ ((row >> 1) & 3);
      bfr[n].s = *(const short8*)&lsB[buf][row * 32 + phys * 8];
    }
#pragma unroll
    for (int m = 0; m < 4; ++m)
#pragma unroll
      for (int n = 0; n < 4; ++n)
        acc[m][n] = __builtin_amdgcn_mfma_f32_16x16x32_bf16(afr[m].s, bfr[n].s, acc[m][n], 0, 0, 0);

    writeA(buf ^ 1, arWrite);           // A(t+1): full-iter cover; implicit vmcnt(5)
    // retire B(t+1)x4; keep A(t+2) in flight across the barrier
    asm volatile("s_waitcnt vmcnt(1) lgkmcnt(0)" ::: "memory");
    __builtin_amdgcn_s_barrier();
    __builtin_amdgcn_sched_barrier(0);
  };

  int t = 0;
  for (; t + 1 < nkt; t += 2) {
    body(t,     0, arE, arO);   // read buf0; load->E(t+2); write O=A(t+1)
    body(t + 1, 1, arO, arE);   // read buf1; load->O;      write E
  }
  if (t < nkt) body(t, 0, arE, arO);    // odd tail (ks==0, nkt=79)

  float* outp = partial + ((size_t)ks * B_DIM + m0) * H1_DIM;
#pragma unroll
  for (int m = 0; m < 4; ++m)
#pragma unroll
    for (int n = 0; n < 4; ++n)
#pragma unroll
      for (int r = 0; r < 4; ++r) {
        int row = m * 16 + j4 * 4 + r;
        int col = w * 64 + n * 16 + c15;
        outp[(size_t)row * H1_DIM + col] = acc[m][n][r];
      }
}

// ---------------- K1b: sum 8 partials + bias + relu -> h1 bf16 ----------------
__global__ void k_reduce1(const float* __restrict__ partial, const float* __restrict__ b1,
                          u16* __restrict__ h1b) {
  const int n4 = B_DIM * H1_DIM / 4;
  int i = blockIdx.x * 256 + threadIdx.x;
  if (i >= n4) return;
  f32x4 s = ((const f32x4*)partial)[i];
#pragma unroll
  for (int k = 1; k < SPLITK; ++k) {
    f32x4 v = ((const f32x4*)partial)[(size_t)k * n4 + i];
    s[0] += v[0]; s[1] += v[1]; s[2] += v[2]; s[3] += v[3];
  }
  f32x4 bb = ((const f32x4*)b1)[i & (H1_DIM / 4 - 1)];
  u16x4 o;
#pragma unroll
  for (int j = 0; j < 4; ++j)
    o[j] = f2b(fmaxf(s[j] + bb[j], 0.f));
  ((u16x4*)h1b)[i] = o;
}

// ---------------- K2: layer-2 GEMM bf16, bias+relu fused -> h2 bf16 ----------------
__global__ __launch_bounds__(256, 2)
void k_gemm2(const u16* __restrict__ h1b, const u16* __restrict__ W2b,
             const float* __restrict__ b2, u16* __restrict__ h2b) {
  const int m0 = blockIdx.x * 128;
  const int n0 = blockIdx.y * 64;
  const int tid  = threadIdx.x;
  const int lane = tid & 63;
  const int wid  = tid >> 6;
  const int wr = wid >> 1, wc = wid & 1;
  const int c15 = lane & 15, j4 = lane >> 4;

  __shared__ u16 lsA[2][128 * 32];
  __shared__ u16 lsB[2][64 * 32];

  f32x4 zero = {0.f, 0.f, 0.f, 0.f};
  f32x4 acc[4][2];
#pragma unroll
  for (int m = 0; m < 4; ++m) { acc[m][0] = zero; acc[m][1] = zero; }

  auto stage = [&](int buf, int kt) {
    const int k0 = kt * 32;
#pragma unroll
    for (int c = 0; c < 2; ++c) {
      int lin = c * 256 + tid;
      int row = lin >> 2, slot = lin & 3;
      int gslot = slot ^ ((row >> 1) & 3);
      gld16(h1b + (size_t)(m0 + row) * H1_DIM + k0 + gslot * 8, &lsA[buf][lin * 8]);
    }
    {
      int lin = tid;
      int row = lin >> 2, slot = lin & 3;
      int gslot = slot ^ ((row >> 1) & 3);
      gld16(W2b + (size_t)(n0 + row) * H1_DIM + k0 + gslot * 8, &lsB[buf][lin * 8]);
    }
  };

  stage(0, 0);
  __syncthreads();
  int buf = 0;
  const int nkt = H1_DIM / 32;   // 16
  for (int t = 0; t < nkt; ++t) {
    if (t + 1 < nkt) stage(buf ^ 1, t + 1);
    Frag bfr[2];
#pragma unroll
    for (int n = 0; n < 2; ++n) {
      int row = wc * 32 + n * 16 + c15;
      int slot = j4 ^ ((row >> 1) & 3);
      bfr[n].s = *(const short8*)&lsB[buf][row * 32 + slot * 8];
    }
    Frag afr[4];
#pragma unroll
    for (int m = 0; m < 4; ++m) {
      int row = wr * 64 + m * 16 + c15;
      int slot = j4 ^ ((row >> 1) & 3);
      afr[m].s = *(const short8*)&lsA[buf][row * 32 + slot * 8];
    }
#pragma unroll
    for (int m = 0; m < 4; ++m)
#pragma unroll
      for (int n = 0; n < 2; ++n)
        acc[m][n] = __builtin_amdgcn_mfma_f32_16x16x32_bf16(afr[m].s, bfr[n].s, acc[m][n], 0, 0, 0);
    __syncthreads();
    buf ^= 1;
  }

  float b2v[2];
  b2v[0] = b2[n0 + wc * 32 + c15];
  b2v[1] = b2[n0 + wc * 32 + 16 + c15];
#pragma unroll
  for (int m = 0; m < 4; ++m)
#pragma unroll
    for (int n = 0; n < 2; ++n)
#pragma unroll
      for (int r = 0; r < 4; ++r) {
        int row = m0 + wr * 64 + m * 16 + j4 * 4 + r;
        int col = n0 + wc * 32 + n * 16 + c15;
        h2b[(size_t)row * H2_DIM + col] = f2b(fmaxf(acc[m][n][r] + b2v[n], 0.f));
      }
}

// ---------------- K3: fused heads ----------------
__global__ __launch_bounds__(256, 2)
void k_heads(const u16* __restrict__ h2b, const u16* __restrict__ W3T,
             const float* __restrict__ b3, const float* __restrict__ W4,
             const float* __restrict__ b4, float* __restrict__ out) {
  const int m0 = blockIdx.x * 128;
  const int p0 = blockIdx.y * 2;
  const int tid  = threadIdx.x;
  const int lane = tid & 63;
  const int wid  = tid >> 6;
  const int wr = wid >> 1, wc = wid & 1;
  const int c15 = lane & 15, j4 = lane >> 4;

  __shared__ u16 lsA[2][128 * 64];
  __shared__ u16 lsB[2][128 * 64];

  f32x4 zero = {0.f, 0.f, 0.f, 0.f};
  f32x4 acc[4][4];
#pragma unroll
  for (int m = 0; m < 4; ++m)
#pragma unroll
    for (int n = 0; n < 4; ++n) acc[m][n] = zero;

  auto stage = [&](int buf, int kt) {
    const int k0 = kt * 64;
#pragma unroll
    for (int c = 0; c < 4; ++c) {
      int lin = c * 256 + tid;
      int row = lin >> 3, slot = lin & 7;
      int gslot = slot ^ (row & 7);
      gld16(h2b + (size_t)(m0 + row) * H2_DIM + k0 + gslot * 8, &lsA[buf][lin * 8]);
    }
#pragma unroll
    for (int c = 0; c < 4; ++c) {
      int lin = c * 256 + tid;
      int row = lin >> 3, slot = lin & 7;
      int gslot = slot ^ (row & 7);
      gld16(W3T + ((size_t)(p0 * 64 + row)) * H2_DIM + k0 + gslot * 8, &lsB[buf][lin * 8]);
    }
  };

  stage(0, 0);
  __syncthreads();
  int buf = 0;
  const int nkt = H2_DIM / 64;   // 4
  for (int t = 0; t < nkt; ++t) {
    if (t + 1 < nkt) stage(buf ^ 1, t + 1);
#pragma unroll
    for (int kk = 0; kk < 2; ++kk) {
      Frag bfr[4];
#pragma unroll
      for (int n = 0; n < 4; ++n) {
        int row = wc * 64 + n * 16 + c15;
        int slot = (kk * 4 + j4) ^ (row & 7);
        bfr[n].s = *(const short8*)&lsB[buf][row * 64 + slot * 8];
      }
      Frag afr[4];
#pragma unroll
      for (int m = 0; m < 4; ++m) {
        int row = wr * 64 + m * 16 + c15;
        int slot = (kk * 4 + j4) ^ (row & 7);
        afr[m].s = *(const short8*)&lsA[buf][row * 64 + slot * 8];
      }
#pragma unroll
      for (int m = 0; m < 4; ++m)
#pragma unroll
        for (int n = 0; n < 4; ++n)
          acc[m][n] = __builtin_amdgcn_mfma_f32_16x16x32_bf16(afr[m].s, bfr[n].s, acc[m][n], 0, 0, 0);
    }
    __syncthreads();
    buf ^= 1;
  }

  const int p = p0 + wc;
  float w4v[4], b3v[4];
#pragma unroll
  for (int n = 0; n < 4; ++n) {
    w4v[n] = W4[p * A_DIM + n * 16 + c15];
    b3v[n] = b3[p * A_DIM + n * 16 + c15];
  }
  const float b4v = b4[p];

  float s[4][4];
#pragma unroll
  for (int m = 0; m < 4; ++m)
#pragma unroll
    for (int r = 0; r < 4; ++r) s[m][r] = 0.f;
#pragma unroll
  for (int m = 0; m < 4; ++m)
#pragma unroll
    for (int n = 0; n < 4; ++n)
#pragma unroll
      for (int r = 0; r < 4; ++r) {
        float v = fmaxf(acc[m][n][r] + b3v[n], 0.f);
        s[m][r] += v * w4v[n];
      }
#pragma unroll
  for (int m = 0; m < 4; ++m)
#pragma unroll
    for (int r = 0; r < 4; ++r) {
      float v = s[m][r];
      v += __shfl_xor(v, 1);
      v += __shfl_xor(v, 2);
      v += __shfl_xor(v, 4);
      v += __shfl_xor(v, 8);
      s[m][r] = v;
    }
  if (c15 == 0) {
#pragma unroll
    for (int m = 0; m < 4; ++m)
#pragma unroll
      for (int r = 0; r < 4; ++r) {
        int row = m0 + wr * 64 + m * 16 + j4 * 4 + r;
        out[(size_t)row * P_DIM + p] = s[m][r] + b4v;
      }
  }
}

extern "C" void kernel_launch(void* const* d_in, const int* in_sizes, int n_in,
                              void* d_out, int out_size, void* d_ws, size_t ws_size,
                              hipStream_t stream) {
  const float* x  = (const float*)d_in[0];
  const float* W1 = (const float*)d_in[1];
  const float* b1 = (const float*)d_in[2];
  const float* W2 = (const float*)d_in[3];
  const float* b2 = (const float*)d_in[4];
  const float* W3 = (const float*)d_in[5];
  const float* b3 = (const float*)d_in[6];
  const float* W4 = (const float*)d_in[7];
  const float* b4 = (const float*)d_in[8];
  float* out = (float*)d_out;

  char* ws = (char*)d_ws;
  u16*   W1b  = (u16*)(ws);                    // 20,480,000 B
  u16*   W2b  = (u16*)(ws + 20480000);         //    262,144 B
  u16*   W3T  = (u16*)(ws + 20742144);         //  4,194,304 B
  u16*   h1b  = (u16*)(ws + 24936448);         //  8,388,608 B
  u16*   h2b  = (u16*)(ws + 33325056);         //  4,194,304 B
  float* part = (float*)(ws + 37519360);       // 8 x 16 MB = 134,217,728 B (end ~172 MB)

  k_convert<<<dim3(10240000 / 4 / 256), dim3(256), 0, stream>>>(W1, W1b, 10240000 / 4);
  k_convert<<<dim3(131072 / 4 / 256), dim3(256), 0, stream>>>(W2, W2b, 131072 / 4);
  k_transpose_w3<<<dim3(2097152 / 256), dim3(256), 0, stream>>>(W3, W3T);

  k_gemm1<<<dim3(128 * SPLITK), dim3(512), 0, stream>>>(x, W1b, part);
  k_reduce1<<<dim3(B_DIM * H1_DIM / 4 / 256), dim3(256), 0, stream>>>(part, b1, h1b);
  k_gemm2<<<dim3(64, 4), dim3(256), 0, stream>>>(h1b, W2b, b2, h2b);
  k_heads<<<dim3(64, 64), dim3(256), 0, stream>>>(h2b, W3T, b3, W4, b4, out);
}

// Round 9
// 374.331 us; speedup vs baseline: 1.3450x; 1.3450x over previous
//
#include <hip/hip_runtime.h>
#include <hip/hip_bf16.h>
#include <stdint.h>

typedef unsigned short u16;
typedef __attribute__((ext_vector_type(8))) short short8;
typedef __attribute__((ext_vector_type(8))) u16   u16x8;
typedef __attribute__((ext_vector_type(4))) u16   u16x4;
typedef __attribute__((ext_vector_type(4))) float f32x4;

#define B_DIM  8192
#define G_DIM  20000
#define H1_DIM 512
#define H2_DIM 256
#define P_DIM  128
#define A_DIM  64
#define SPLITK 8
#define NKT_ALL 625   // 20000 / 32

union Frag { short8 s; u16x8 u; };

__device__ __forceinline__ u16 f2b(float f) {
  union { __hip_bfloat16 b; u16 u; } c;
  c.b = __float2bfloat16(f);
  return c.u;
}

__device__ __forceinline__ void gld16(const void* g, void* l) {
  __builtin_amdgcn_global_load_lds(
      (const __attribute__((address_space(1))) void*)g,
      (__attribute__((address_space(3))) void*)l, 16, 0, 0);
}

// ---------------- prep: f32 -> bf16 convert (vectorized) ----------------
__global__ void k_convert(const float* __restrict__ src, u16* __restrict__ dst, int n4) {
  int i = blockIdx.x * 256 + threadIdx.x;
  if (i >= n4) return;
  f32x4 v = ((const f32x4*)src)[i];
  u16x4 o;
  o[0] = f2b(v[0]); o[1] = f2b(v[1]);
  o[2] = f2b(v[2]); o[3] = f2b(v[3]);
  ((u16x4*)dst)[i] = o;
}

// ---------------- prep: W1 f32 -> MFMA-fragment-linear bf16 ----------------
// W1f element layout (u16x8 chunk index ot):
//   ot = (rowblk*625 + kt)*64 + lane,  chunk = W1[rowblk*16 + (lane&15)]
//                                            [kt*32 + (lane>>4)*8 + 0..7]
// In K1, lane `l` of the B-frag for (rowblk, kt) reads chunk ot -> one
// coalesced 1KB load per wave, exactly the mfma_16x16x32 B operand.
__global__ void k_convert_w1frag(const float* __restrict__ W1, u16* __restrict__ W1f) {
  int ot = blockIdx.x * 256 + threadIdx.x;       // 0 .. 1,279,999
  if (ot >= (H1_DIM / 16) * NKT_ALL * 64) return;
  int rowblk = ot / (NKT_ALL * 64);
  int rem    = ot - rowblk * (NKT_ALL * 64);
  int kt     = rem >> 6;
  int lane   = rem & 63;
  int row = rowblk * 16 + (lane & 15);
  int col = kt * 32 + (lane >> 4) * 8;
  const float* src = W1 + (size_t)row * G_DIM + col;
  f32x4 v0 = *(const f32x4*)src;
  f32x4 v1 = *(const f32x4*)(src + 4);
  u16x8 o;
#pragma unroll
  for (int i = 0; i < 4; ++i) { o[i] = f2b(v0[i]); o[i + 4] = f2b(v1[i]); }
  ((u16x8*)W1f)[ot] = o;
}

// ---------------- prep: W3[p][h][a] f32 -> W3T[p][a][h] bf16 ----------------
__global__ void k_transpose_w3(const float* __restrict__ W3, u16* __restrict__ W3T) {
  int idx = blockIdx.x * 256 + threadIdx.x;     // = (p*64+a)*256 + h
  if (idx >= P_DIM * H2_DIM * A_DIM) return;
  int h = idx & (H2_DIM - 1);
  int a = (idx >> 8) & (A_DIM - 1);
  int p = idx >> 14;
  W3T[idx] = f2b(W3[((size_t)p * H2_DIM + h) * A_DIM + a]);
}

// ---------------- K1: layer-1 GEMM ----------------
// BM=64, BN=512 (X read once), BK=32, SPLITK=8 via ks=blockIdx&7 (XCD-pinned
// W1f slice 2.56MB -> L2-resident; R7-verified).
// R9: B NEVER touches LDS -- per-wave coalesced 1KB frag loads from W1f
// (wave-private data; LDS staging bought nothing). LDS = 8KB (A only) ->
// lean blocks, B waits are compiler-tracked reg deps, barrier covers only
// the tiny A tile. A reg-staged 2-deep; counted vmcnt(1) keeps the lone
// A(t+2) HBM load in flight across the barrier.
__global__ __launch_bounds__(512, 4)   // 4 waves/EU; VGPR cap 128; 2 blocks/CU
void k_gemm1(const float* __restrict__ X, const u16* __restrict__ W1f,
             float* __restrict__ partial) {
  const int ks = blockIdx.x & 7;
  const int m0 = (blockIdx.x >> 3) * 64;
  const int kt_begin = (ks == 0) ? 0 : (ks * 78 + 1);   // {79, 78x7} of 625
  const int nkt = (ks == 0) ? 79 : 78;

  const int tid  = threadIdx.x;
  const int lane = tid & 63;
  const int w    = tid >> 6;            // wave 0..7 -> N rows w*64..
  const int c15 = lane & 15, j4 = lane >> 4;
  const int w4 = w * 4;

  __shared__ u16 lsA[2][64 * 32];       // 4 KB/buf; row = 64B = 4 slots x 16B

  // A staging: thread -> row tid>>3, granule tid&7 (16B f32 load -> 8B LDS)
  const int aRow = tid >> 3;
  const int aG   = tid & 7;
  const int aPhysU16 = aRow * 32 + (((aG >> 1) ^ ((aRow >> 1) & 3)) << 3) + ((aG & 1) << 2);
  const float* aSrc0 = X + (size_t)(m0 + aRow) * G_DIM + aG * 4;

  f32x4 zero = {0.f, 0.f, 0.f, 0.f};
  f32x4 acc[4][4];
#pragma unroll
  for (int m = 0; m < 4; ++m)
#pragma unroll
    for (int n = 0; n < 4; ++n) acc[m][n] = zero;

  auto ktc = [&](int t) { return kt_begin + (t < nkt ? t : nkt - 1); };

  auto loadA = [&](int kt, f32x4& ar) {
    ar = *(const f32x4*)(aSrc0 + (size_t)kt * 32);
  };
  auto writeA = [&](int buf, const f32x4& ar) {
    u16x4 o;
    o[0] = f2b(ar[0]); o[1] = f2b(ar[1]); o[2] = f2b(ar[2]); o[3] = f2b(ar[3]);
    *(u16x4*)&lsA[buf][aPhysU16] = o;
  };

  f32x4 arE, arO;   // 2-deep A pipeline

  // ---- prologue ----
  loadA(ktc(0), arE);
  loadA(ktc(1), arO);
  writeA(0, arE);                       // compiler waits A0; A1 stays in flight
  asm volatile("s_waitcnt vmcnt(1) lgkmcnt(0)" ::: "memory");
  __builtin_amdgcn_s_barrier();
  __builtin_amdgcn_sched_barrier(0);

  auto body = [&](int t, int buf, f32x4& arLoad, const f32x4& arWrite) {
    const int kt = kt_begin + t;
    // B(t): 4 coalesced per-wave frag loads (L2-resident slice), reg-direct
    Frag bfr[4];
#pragma unroll
    for (int n = 0; n < 4; ++n)
      bfr[n].s = *(const short8*)(W1f + ((size_t)((w4 + n) * NKT_ALL + kt) * 64 + lane) * 8);
    // A(t+2) -> regs; crosses the next barrier in flight
    loadA(ktc(t + 2), arLoad);

    Frag afr[4];
#pragma unroll
    for (int m = 0; m < 4; ++m) {
      int row = m * 16 + c15;
      int phys = j4 ^ ((row >> 1) & 3);
      afr[m].s = *(const short8*)&lsA[buf][row * 32 + phys * 8];
    }
    writeA(buf ^ 1, arWrite);           // A(t+1) -> other buffer (1-iter-old load)

#pragma unroll
    for (int m = 0; m < 4; ++m)
#pragma unroll
      for (int n = 0; n < 4; ++n)
        acc[m][n] = __builtin_amdgcn_mfma_f32_16x16x32_bf16(afr[m].s, bfr[n].s, acc[m][n], 0, 0, 0);

    // B(t) retired by MFMA waits; only A(t+2) stays across the barrier
    asm volatile("s_waitcnt vmcnt(1) lgkmcnt(0)" ::: "memory");
    __builtin_amdgcn_s_barrier();
    __builtin_amdgcn_sched_barrier(0);
  };

  int t = 0;
  for (; t + 1 < nkt; t += 2) {
    body(t,     0, arE, arO);
    body(t + 1, 1, arO, arE);
  }
  if (t < nkt) body(t, 0, arE, arO);    // odd tail (ks==0, nkt=79)

  float* outp = partial + ((size_t)ks * B_DIM + m0) * H1_DIM;
#pragma unroll
  for (int m = 0; m < 4; ++m)
#pragma unroll
    for (int n = 0; n < 4; ++n)
#pragma unroll
      for (int r = 0; r < 4; ++r) {
        int row = m * 16 + j4 * 4 + r;
        int col = w * 64 + n * 16 + c15;
        outp[(size_t)row * H1_DIM + col] = acc[m][n][r];
      }
}

// ---------------- K1b: sum 8 partials + bias + relu -> h1 bf16 ----------------
__global__ void k_reduce1(const float* __restrict__ partial, const float* __restrict__ b1,
                          u16* __restrict__ h1b) {
  const int n4 = B_DIM * H1_DIM / 4;
  int i = blockIdx.x * 256 + threadIdx.x;
  if (i >= n4) return;
  f32x4 s = ((const f32x4*)partial)[i];
#pragma unroll
  for (int k = 1; k < SPLITK; ++k) {
    f32x4 v = ((const f32x4*)partial)[(size_t)k * n4 + i];
    s[0] += v[0]; s[1] += v[1]; s[2] += v[2]; s[3] += v[3];
  }
  f32x4 bb = ((const f32x4*)b1)[i & (H1_DIM / 4 - 1)];
  u16x4 o;
#pragma unroll
  for (int j = 0; j < 4; ++j)
    o[j] = f2b(fmaxf(s[j] + bb[j], 0.f));
  ((u16x4*)h1b)[i] = o;
}

// ---------------- K2: layer-2 GEMM bf16, bias+relu fused -> h2 bf16 ----------------
__global__ __launch_bounds__(256, 2)
void k_gemm2(const u16* __restrict__ h1b, const u16* __restrict__ W2b,
             const float* __restrict__ b2, u16* __restrict__ h2b) {
  const int m0 = blockIdx.x * 128;
  const int n0 = blockIdx.y * 64;
  const int tid  = threadIdx.x;
  const int lane = tid & 63;
  const int wid  = tid >> 6;
  const int wr = wid >> 1, wc = wid & 1;
  const int c15 = lane & 15, j4 = lane >> 4;

  __shared__ u16 lsA[2][128 * 32];
  __shared__ u16 lsB[2][64 * 32];

  f32x4 zero = {0.f, 0.f, 0.f, 0.f};
  f32x4 acc[4][2];
#pragma unroll
  for (int m = 0; m < 4; ++m) { acc[m][0] = zero; acc[m][1] = zero; }

  auto stage = [&](int buf, int kt) {
    const int k0 = kt * 32;
#pragma unroll
    for (int c = 0; c < 2; ++c) {
      int lin = c * 256 + tid;
      int row = lin >> 2, slot = lin & 3;
      int gslot = slot ^ ((row >> 1) & 3);
      gld16(h1b + (size_t)(m0 + row) * H1_DIM + k0 + gslot * 8, &lsA[buf][lin * 8]);
    }
    {
      int lin = tid;
      int row = lin >> 2, slot = lin & 3;
      int gslot = slot ^ ((row >> 1) & 3);
      gld16(W2b + (size_t)(n0 + row) * H1_DIM + k0 + gslot * 8, &lsB[buf][lin * 8]);
    }
  };

  stage(0, 0);
  __syncthreads();
  int buf = 0;
  const int nkt = H1_DIM / 32;   // 16
  for (int t = 0; t < nkt; ++t) {
    if (t + 1 < nkt) stage(buf ^ 1, t + 1);
    Frag bfr[2];
#pragma unroll
    for (int n = 0; n < 2; ++n) {
      int row = wc * 32 + n * 16 + c15;
      int slot = j4 ^ ((row >> 1) & 3);
      bfr[n].s = *(const short8*)&lsB[buf][row * 32 + slot * 8];
    }
    Frag afr[4];
#pragma unroll
    for (int m = 0; m < 4; ++m) {
      int row = wr * 64 + m * 16 + c15;
      int slot = j4 ^ ((row >> 1) & 3);
      afr[m].s = *(const short8*)&lsA[buf][row * 32 + slot * 8];
    }
#pragma unroll
    for (int m = 0; m < 4; ++m)
#pragma unroll
      for (int n = 0; n < 2; ++n)
        acc[m][n] = __builtin_amdgcn_mfma_f32_16x16x32_bf16(afr[m].s, bfr[n].s, acc[m][n], 0, 0, 0);
    __syncthreads();
    buf ^= 1;
  }

  float b2v[2];
  b2v[0] = b2[n0 + wc * 32 + c15];
  b2v[1] = b2[n0 + wc * 32 + 16 + c15];
#pragma unroll
  for (int m = 0; m < 4; ++m)
#pragma unroll
    for (int n = 0; n < 2; ++n)
#pragma unroll
      for (int r = 0; r < 4; ++r) {
        int row = m0 + wr * 64 + m * 16 + j4 * 4 + r;
        int col = n0 + wc * 32 + n * 16 + c15;
        h2b[(size_t)row * H2_DIM + col] = f2b(fmaxf(acc[m][n][r] + b2v[n], 0.f));
      }
}

// ---------------- K3: fused heads ----------------
__global__ __launch_bounds__(256, 2)
void k_heads(const u16* __restrict__ h2b, const u16* __restrict__ W3T,
             const float* __restrict__ b3, const float* __restrict__ W4,
             const float* __restrict__ b4, float* __restrict__ out) {
  const int m0 = blockIdx.x * 128;
  const int p0 = blockIdx.y * 2;
  const int tid  = threadIdx.x;
  const int lane = tid & 63;
  const int wid  = tid >> 6;
  const int wr = wid >> 1, wc = wid & 1;
  const int c15 = lane & 15, j4 = lane >> 4;

  __shared__ u16 lsA[2][128 * 64];
  __shared__ u16 lsB[2][128 * 64];

  f32x4 zero = {0.f, 0.f, 0.f, 0.f};
  f32x4 acc[4][4];
#pragma unroll
  for (int m = 0; m < 4; ++m)
#pragma unroll
    for (int n = 0; n < 4; ++n) acc[m][n] = zero;

  auto stage = [&](int buf, int kt) {
    const int k0 = kt * 64;
#pragma unroll
    for (int c = 0; c < 4; ++c) {
      int lin = c * 256 + tid;
      int row = lin >> 3, slot = lin & 7;
      int gslot = slot ^ (row & 7);
      gld16(h2b + (size_t)(m0 + row) * H2_DIM + k0 + gslot * 8, &lsA[buf][lin * 8]);
    }
#pragma unroll
    for (int c = 0; c < 4; ++c) {
      int lin = c * 256 + tid;
      int row = lin >> 3, slot = lin & 7;
      int gslot = slot ^ (row & 7);
      gld16(W3T + ((size_t)(p0 * 64 + row)) * H2_DIM + k0 + gslot * 8, &lsB[buf][lin * 8]);
    }
  };

  stage(0, 0);
  __syncthreads();
  int buf = 0;
  const int nkt = H2_DIM / 64;   // 4
  for (int t = 0; t < nkt; ++t) {
    if (t + 1 < nkt) stage(buf ^ 1, t + 1);
#pragma unroll
    for (int kk = 0; kk < 2; ++kk) {
      Frag bfr[4];
#pragma unroll
      for (int n = 0; n < 4; ++n) {
        int row = wc * 64 + n * 16 + c15;
        int slot = (kk * 4 + j4) ^ (row & 7);
        bfr[n].s = *(const short8*)&lsB[buf][row * 64 + slot * 8];
      }
      Frag afr[4];
#pragma unroll
      for (int m = 0; m < 4; ++m) {
        int row = wr * 64 + m * 16 + c15;
        int slot = (kk * 4 + j4) ^ (row & 7);
        afr[m].s = *(const short8*)&lsA[buf][row * 64 + slot * 8];
      }
#pragma unroll
      for (int m = 0; m < 4; ++m)
#pragma unroll
        for (int n = 0; n < 4; ++n)
          acc[m][n] = __builtin_amdgcn_mfma_f32_16x16x32_bf16(afr[m].s, bfr[n].s, acc[m][n], 0, 0, 0);
    }
    __syncthreads();
    buf ^= 1;
  }

  const int p = p0 + wc;
  float w4v[4], b3v[4];
#pragma unroll
  for (int n = 0; n < 4; ++n) {
    w4v[n] = W4[p * A_DIM + n * 16 + c15];
    b3v[n] = b3[p * A_DIM + n * 16 + c15];
  }
  const float b4v = b4[p];

  float s[4][4];
#pragma unroll
  for (int m = 0; m < 4; ++m)
#pragma unroll
    for (int r = 0; r < 4; ++r) s[m][r] = 0.f;
#pragma unroll
  for (int m = 0; m < 4; ++m)
#pragma unroll
    for (int n = 0; n < 4; ++n)
#pragma unroll
      for (int r = 0; r < 4; ++r) {
        float v = fmaxf(acc[m][n][r] + b3v[n], 0.f);
        s[m][r] += v * w4v[n];
      }
#pragma unroll
  for (int m = 0; m < 4; ++m)
#pragma unroll
    for (int r = 0; r < 4; ++r) {
      float v = s[m][r];
      v += __shfl_xor(v, 1);
      v += __shfl_xor(v, 2);
      v += __shfl_xor(v, 4);
      v += __shfl_xor(v, 8);
      s[m][r] = v;
    }
  if (c15 == 0) {
#pragma unroll
    for (int m = 0; m < 4; ++m)
#pragma unroll
      for (int r = 0; r < 4; ++r) {
        int row = m0 + wr * 64 + m * 16 + j4 * 4 + r;
        out[(size_t)row * P_DIM + p] = s[m][r] + b4v;
      }
  }
}

extern "C" void kernel_launch(void* const* d_in, const int* in_sizes, int n_in,
                              void* d_out, int out_size, void* d_ws, size_t ws_size,
                              hipStream_t stream) {
  const float* x  = (const float*)d_in[0];
  const float* W1 = (const float*)d_in[1];
  const float* b1 = (const float*)d_in[2];
  const float* W2 = (const float*)d_in[3];
  const float* b2 = (const float*)d_in[4];
  const float* W3 = (const float*)d_in[5];
  const float* b3 = (const float*)d_in[6];
  const float* W4 = (const float*)d_in[7];
  const float* b4 = (const float*)d_in[8];
  float* out = (float*)d_out;

  char* ws = (char*)d_ws;
  u16*   W1f  = (u16*)(ws);                    // 20,480,000 B (fragment-linear)
  u16*   W2b  = (u16*)(ws + 20480000);         //    262,144 B
  u16*   W3T  = (u16*)(ws + 20742144);         //  4,194,304 B
  u16*   h1b  = (u16*)(ws + 24936448);         //  8,388,608 B
  u16*   h2b  = (u16*)(ws + 33325056);         //  4,194,304 B
  float* part = (float*)(ws + 37519360);       // 8 x 16 MB = 134,217,728 B (end ~172 MB)

  k_convert_w1frag<<<dim3((1280000 + 255) / 256), dim3(256), 0, stream>>>(W1, W1f);
  k_convert<<<dim3(131072 / 4 / 256), dim3(256), 0, stream>>>(W2, W2b, 131072 / 4);
  k_transpose_w3<<<dim3(2097152 / 256), dim3(256), 0, stream>>>(W3, W3T);

  k_gemm1<<<dim3(128 * SPLITK), dim3(512), 0, stream>>>(x, W1f, part);
  k_reduce1<<<dim3(B_DIM * H1_DIM / 4 / 256), dim3(256), 0, stream>>>(part, b1, h1b);
  k_gemm2<<<dim3(64, 4), dim3(256), 0, stream>>>(h1b, W2b, b2, h2b);
  k_heads<<<dim3(64, 64), dim3(256), 0, stream>>>(h2b, W3T, b3, W4, b4, out);
}

// Round 10
// 373.193 us; speedup vs baseline: 1.3491x; 1.0030x over previous
//
#include <hip/hip_runtime.h>
#include <hip/hip_bf16.h>
#include <stdint.h>

typedef unsigned short u16;
typedef __attribute__((ext_vector_type(8))) short short8;
typedef __attribute__((ext_vector_type(8))) u16   u16x8;
typedef __attribute__((ext_vector_type(4))) u16   u16x4;
typedef __attribute__((ext_vector_type(4))) float f32x4;

#define B_DIM  8192
#define G_DIM  20000
#define H1_DIM 512
#define H2_DIM 256
#define P_DIM  128
#define A_DIM  64
#define SPLITK 8
#define NKT_ALL 625   // 20000 / 32

union Frag { short8 s; u16x8 u; };

__device__ __forceinline__ u16 f2b(float f) {
  union { __hip_bfloat16 b; u16 u; } c;
  c.b = __float2bfloat16(f);
  return c.u;
}

__device__ __forceinline__ void gld16(const void* g, void* l) {
  __builtin_amdgcn_global_load_lds(
      (const __attribute__((address_space(1))) void*)g,
      (__attribute__((address_space(3))) void*)l, 16, 0, 0);
}

// ---------------- prep: f32 -> bf16 convert (vectorized) ----------------
__global__ void k_convert(const float* __restrict__ src, u16* __restrict__ dst, int n4) {
  int i = blockIdx.x * 256 + threadIdx.x;
  if (i >= n4) return;
  f32x4 v = ((const f32x4*)src)[i];
  u16x4 o;
  o[0] = f2b(v[0]); o[1] = f2b(v[1]);
  o[2] = f2b(v[2]); o[3] = f2b(v[3]);
  ((u16x4*)dst)[i] = o;
}

// ---------------- prep: W1 f32 -> MFMA-fragment-linear bf16 ----------------
// chunk ot = (rowblk*625 + kt)*64 + lane  ->  W1[rowblk*16 + (lane&15)]
//                                             [kt*32 + (lane>>4)*8 + 0..7]
__global__ void k_convert_w1frag(const float* __restrict__ W1, u16* __restrict__ W1f) {
  int ot = blockIdx.x * 256 + threadIdx.x;       // 0 .. 1,279,999
  if (ot >= (H1_DIM / 16) * NKT_ALL * 64) return;
  int rowblk = ot / (NKT_ALL * 64);
  int rem    = ot - rowblk * (NKT_ALL * 64);
  int kt     = rem >> 6;
  int lane   = rem & 63;
  int row = rowblk * 16 + (lane & 15);
  int col = kt * 32 + (lane >> 4) * 8;
  const float* src = W1 + (size_t)row * G_DIM + col;
  f32x4 v0 = *(const f32x4*)src;
  f32x4 v1 = *(const f32x4*)(src + 4);
  u16x8 o;
#pragma unroll
  for (int i = 0; i < 4; ++i) { o[i] = f2b(v0[i]); o[i + 4] = f2b(v1[i]); }
  ((u16x8*)W1f)[ot] = o;
}

// ---------------- prep: W3[p][h][a] f32 -> W3T[p][a][h] bf16 ----------------
__global__ void k_transpose_w3(const float* __restrict__ W3, u16* __restrict__ W3T) {
  int idx = blockIdx.x * 256 + threadIdx.x;     // = (p*64+a)*256 + h
  if (idx >= P_DIM * H2_DIM * A_DIM) return;
  int h = idx & (H2_DIM - 1);
  int a = (idx >> 8) & (A_DIM - 1);
  int p = idx >> 14;
  W3T[idx] = f2b(W3[((size_t)p * H2_DIM + h) * A_DIM + a]);
}

// ---------------- K1: layer-1 GEMM ----------------
// R10: BK=64 super-iteration (2 kt per barrier, 39 barriers), B fragments
// reg-prefetched across the barrier (no vmcnt asm at all), A staged via a
// 64x64 f32->bf16 LDS tile (16 KB total). ks=blockIdx&7 XCD-pins the W1f
// slice (2.56 MB, L2-resident). Sync = lgkmcnt(0) + s_barrier only.
__global__ __launch_bounds__(512, 4)   // 4 waves/EU; VGPR cap 128; 2 blocks/CU
void k_gemm1(const float* __restrict__ X, const u16* __restrict__ W1f,
             float* __restrict__ partial) {
  const int ks = blockIdx.x & 7;
  const int m0 = (blockIdx.x >> 3) * 64;
  const int kt_begin = (ks == 0) ? 0 : (ks * 78 + 1);   // {79, 78x7} of 625
  const int nkt = (ks == 0) ? 79 : 78;

  const int tid  = threadIdx.x;
  const int lane = tid & 63;
  const int w    = tid >> 6;
  const int c15 = lane & 15, j4 = lane >> 4;
  const int w4 = w * 4;

  __shared__ u16 lsA[2][64 * 64];   // 8 KB/buf: 64 rows x 128B (8 slots of 16B)
                                    // phys slot = g ^ (row&7)  (uniform -> conflict-free)

  // A staging: thread -> row tid>>3, granule g=tid&7 (8 f32 = 2 f32x4 loads -> 8 bf16)
  const int aRow = tid >> 3;
  const int aG   = tid & 7;
  const int aPhysU16 = aRow * 64 + ((aG ^ (aRow & 7)) * 8);
  const float* aSrc0 = X + (size_t)(m0 + aRow) * G_DIM + aG * 8;

  f32x4 zero = {0.f, 0.f, 0.f, 0.f};
  f32x4 acc[4][4];
#pragma unroll
  for (int m = 0; m < 4; ++m)
#pragma unroll
    for (int n = 0; n < 4; ++n) acc[m][n] = zero;

  auto loadB = [&](int kt, Frag* br) {
#pragma unroll
    for (int n = 0; n < 4; ++n)
      br[n].s = *(const short8*)(W1f + ((size_t)((w4 + n) * NKT_ALL + kt) * 64 + lane) * 8);
  };
  f32x4 ar0, ar1;   // in-flight A (8 f32 per thread)
  auto loadA = [&](int kt) {       // loads the 64-col (2-kt) tile starting at kt
    const float* src = aSrc0 + (size_t)kt * 32;
    ar0 = *(const f32x4*)src;
    ar1 = *(const f32x4*)(src + 4);
  };
  auto writeA = [&](int buf) {
    u16x8 o;
#pragma unroll
    for (int i = 0; i < 4; ++i) { o[i] = f2b(ar0[i]); o[i + 4] = f2b(ar1[i]); }
    *(u16x8*)&lsA[buf][aPhysU16] = o;
  };
  auto readAfr = [&](int buf, int half, Frag* afr) {
#pragma unroll
    for (int m = 0; m < 4; ++m) {
      int row = m * 16 + c15;
      int g = half * 4 + j4;
      int phys = g ^ (row & 7);
      afr[m].s = *(const short8*)&lsA[buf][row * 64 + phys * 8];
    }
  };

  Frag bfrE[4], bfrO[4];

  // ---- prologue: A-tile 0 (kt 0,1) -> LDS buf0; B(kt0) -> regs ----
  loadA(kt_begin);
  loadB(kt_begin, bfrE);
  writeA(0);                            // waits the A loads
  asm volatile("s_waitcnt lgkmcnt(0)" ::: "memory");
  __builtin_amdgcn_s_barrier();
  __builtin_amdgcn_sched_barrier(0);

  const int nsuper = 39;                // covers kt 0..77 of the slice
  for (int T = 0; T < nsuper; ++T) {
    const int buf = T & 1;
    const int kt0 = kt_begin + 2 * T;
    const int ktN = 2 * (T + 1);
    const int ktNext = kt_begin + ((ktN < nkt) ? ktN : (nkt - 1));

    loadA(ktNext);                      // A tile T+1 (cover: whole body)
    loadB(kt0 + 1, bfrO);               // B kt1 (cover: 16 MFMA)

    Frag afr[4];
    readAfr(buf, 0, afr);
#pragma unroll
    for (int m = 0; m < 4; ++m)
#pragma unroll
      for (int n = 0; n < 4; ++n)
        acc[m][n] = __builtin_amdgcn_mfma_f32_16x16x32_bf16(afr[m].s, bfrE[n].s, acc[m][n], 0, 0, 0);

    loadB(ktNext, bfrE);                // next super's kt0 (crosses barrier in regs)

    readAfr(buf, 1, afr);
#pragma unroll
    for (int m = 0; m < 4; ++m)
#pragma unroll
      for (int n = 0; n < 4; ++n)
        acc[m][n] = __builtin_amdgcn_mfma_f32_16x16x32_bf16(afr[m].s, bfrO[n].s, acc[m][n], 0, 0, 0);

    writeA(buf ^ 1);                    // A tile T+1 (its loads are body-old)
    asm volatile("s_waitcnt lgkmcnt(0)" ::: "memory");
    __builtin_amdgcn_s_barrier();
    __builtin_amdgcn_sched_barrier(0);
  }

  if (nkt == 79) {                      // ks==0 epilogue: kt 78 (staged in buf1 by T=38)
    Frag afr[4];
    readAfr(1, 0, afr);
#pragma unroll
    for (int m = 0; m < 4; ++m)
#pragma unroll
      for (int n = 0; n < 4; ++n)
        acc[m][n] = __builtin_amdgcn_mfma_f32_16x16x32_bf16(afr[m].s, bfrE[n].s, acc[m][n], 0, 0, 0);
  }

  float* outp = partial + ((size_t)ks * B_DIM + m0) * H1_DIM;
#pragma unroll
  for (int m = 0; m < 4; ++m)
#pragma unroll
    for (int n = 0; n < 4; ++n)
#pragma unroll
      for (int r = 0; r < 4; ++r) {
        int row = m * 16 + j4 * 4 + r;
        int col = w * 64 + n * 16 + c15;
        outp[(size_t)row * H1_DIM + col] = acc[m][n][r];
      }
}

// ---------------- K1b: sum 8 partials + bias + relu -> h1 bf16 ----------------
__global__ void k_reduce1(const float* __restrict__ partial, const float* __restrict__ b1,
                          u16* __restrict__ h1b) {
  const int n4 = B_DIM * H1_DIM / 4;
  int i = blockIdx.x * 256 + threadIdx.x;
  if (i >= n4) return;
  f32x4 s = ((const f32x4*)partial)[i];
#pragma unroll
  for (int k = 1; k < SPLITK; ++k) {
    f32x4 v = ((const f32x4*)partial)[(size_t)k * n4 + i];
    s[0] += v[0]; s[1] += v[1]; s[2] += v[2]; s[3] += v[3];
  }
  f32x4 bb = ((const f32x4*)b1)[i & (H1_DIM / 4 - 1)];
  u16x4 o;
#pragma unroll
  for (int j = 0; j < 4; ++j)
    o[j] = f2b(fmaxf(s[j] + bb[j], 0.f));
  ((u16x4*)h1b)[i] = o;
}

// ---------------- K2: layer-2 GEMM bf16, bias+relu fused -> h2 bf16 ----------------
__global__ __launch_bounds__(256, 2)
void k_gemm2(const u16* __restrict__ h1b, const u16* __restrict__ W2b,
             const float* __restrict__ b2, u16* __restrict__ h2b) {
  const int m0 = blockIdx.x * 128;
  const int n0 = blockIdx.y * 64;
  const int tid  = threadIdx.x;
  const int lane = tid & 63;
  const int wid  = tid >> 6;
  const int wr = wid >> 1, wc = wid & 1;
  const int c15 = lane & 15, j4 = lane >> 4;

  __shared__ u16 lsA[2][128 * 32];
  __shared__ u16 lsB[2][64 * 32];

  f32x4 zero = {0.f, 0.f, 0.f, 0.f};
  f32x4 acc[4][2];
#pragma unroll
  for (int m = 0; m < 4; ++m) { acc[m][0] = zero; acc[m][1] = zero; }

  auto stage = [&](int buf, int kt) {
    const int k0 = kt * 32;
#pragma unroll
    for (int c = 0; c < 2; ++c) {
      int lin = c * 256 + tid;
      int row = lin >> 2, slot = lin & 3;
      int gslot = slot ^ ((row >> 1) & 3);
      gld16(h1b + (size_t)(m0 + row) * H1_DIM + k0 + gslot * 8, &lsA[buf][lin * 8]);
    }
    {
      int lin = tid;
      int row = lin >> 2, slot = lin & 3;
      int gslot = slot ^ ((row >> 1) & 3);
      gld16(W2b + (size_t)(n0 + row) * H1_DIM + k0 + gslot * 8, &lsB[buf][lin * 8]);
    }
  };

  stage(0, 0);
  __syncthreads();
  int buf = 0;
  const int nkt = H1_DIM / 32;   // 16
  for (int t = 0; t < nkt; ++t) {
    if (t + 1 < nkt) stage(buf ^ 1, t + 1);
    Frag bfr[2];
#pragma unroll
    for (int n = 0; n < 2; ++n) {
      int row = wc * 32 + n * 16 + c15;
      int slot = j4 ^ ((row >> 1) & 3);
      bfr[n].s = *(const short8*)&lsB[buf][row * 32 + slot * 8];
    }
    Frag afr[4];
#pragma unroll
    for (int m = 0; m < 4; ++m) {
      int row = wr * 64 + m * 16 + c15;
      int slot = j4 ^ ((row >> 1) & 3);
      afr[m].s = *(const short8*)&lsA[buf][row * 32 + slot * 8];
    }
#pragma unroll
    for (int m = 0; m < 4; ++m)
#pragma unroll
      for (int n = 0; n < 2; ++n)
        acc[m][n] = __builtin_amdgcn_mfma_f32_16x16x32_bf16(afr[m].s, bfr[n].s, acc[m][n], 0, 0, 0);
    __syncthreads();
    buf ^= 1;
  }

  float b2v[2];
  b2v[0] = b2[n0 + wc * 32 + c15];
  b2v[1] = b2[n0 + wc * 32 + 16 + c15];
#pragma unroll
  for (int m = 0; m < 4; ++m)
#pragma unroll
    for (int n = 0; n < 2; ++n)
#pragma unroll
      for (int r = 0; r < 4; ++r) {
        int row = m0 + wr * 64 + m * 16 + j4 * 4 + r;
        int col = n0 + wc * 32 + n * 16 + c15;
        h2b[(size_t)row * H2_DIM + col] = f2b(fmaxf(acc[m][n][r] + b2v[n], 0.f));
      }
}

// ---------------- K3: fused heads ----------------
__global__ __launch_bounds__(256, 2)
void k_heads(const u16* __restrict__ h2b, const u16* __restrict__ W3T,
             const float* __restrict__ b3, const float* __restrict__ W4,
             const float* __restrict__ b4, float* __restrict__ out) {
  const int m0 = blockIdx.x * 128;
  const int p0 = blockIdx.y * 2;
  const int tid  = threadIdx.x;
  const int lane = tid & 63;
  const int wid  = tid >> 6;
  const int wr = wid >> 1, wc = wid & 1;
  const int c15 = lane & 15, j4 = lane >> 4;

  __shared__ u16 lsA[2][128 * 64];
  __shared__ u16 lsB[2][128 * 64];

  f32x4 zero = {0.f, 0.f, 0.f, 0.f};
  f32x4 acc[4][4];
#pragma unroll
  for (int m = 0; m < 4; ++m)
#pragma unroll
    for (int n = 0; n < 4; ++n) acc[m][n] = zero;

  auto stage = [&](int buf, int kt) {
    const int k0 = kt * 64;
#pragma unroll
    for (int c = 0; c < 4; ++c) {
      int lin = c * 256 + tid;
      int row = lin >> 3, slot = lin & 7;
      int gslot = slot ^ (row & 7);
      gld16(h2b + (size_t)(m0 + row) * H2_DIM + k0 + gslot * 8, &lsA[buf][lin * 8]);
    }
#pragma unroll
    for (int c = 0; c < 4; ++c) {
      int lin = c * 256 + tid;
      int row = lin >> 3, slot = lin & 7;
      int gslot = slot ^ (row & 7);
      gld16(W3T + ((size_t)(p0 * 64 + row)) * H2_DIM + k0 + gslot * 8, &lsB[buf][lin * 8]);
    }
  };

  stage(0, 0);
  __syncthreads();
  int buf = 0;
  const int nkt = H2_DIM / 64;   // 4
  for (int t = 0; t < nkt; ++t) {
    if (t + 1 < nkt) stage(buf ^ 1, t + 1);
#pragma unroll
    for (int kk = 0; kk < 2; ++kk) {
      Frag bfr[4];
#pragma unroll
      for (int n = 0; n < 4; ++n) {
        int row = wc * 64 + n * 16 + c15;
        int slot = (kk * 4 + j4) ^ (row & 7);
        bfr[n].s = *(const short8*)&lsB[buf][row * 64 + slot * 8];
      }
      Frag afr[4];
#pragma unroll
      for (int m = 0; m < 4; ++m) {
        int row = wr * 64 + m * 16 + c15;
        int slot = (kk * 4 + j4) ^ (row & 7);
        afr[m].s = *(const short8*)&lsA[buf][row * 64 + slot * 8];
      }
#pragma unroll
      for (int m = 0; m < 4; ++m)
#pragma unroll
        for (int n = 0; n < 4; ++n)
          acc[m][n] = __builtin_amdgcn_mfma_f32_16x16x32_bf16(afr[m].s, bfr[n].s, acc[m][n], 0, 0, 0);
    }
    __syncthreads();
    buf ^= 1;
  }

  const int p = p0 + wc;
  float w4v[4], b3v[4];
#pragma unroll
  for (int n = 0; n < 4; ++n) {
    w4v[n] = W4[p * A_DIM + n * 16 + c15];
    b3v[n] = b3[p * A_DIM + n * 16 + c15];
  }
  const float b4v = b4[p];

  float s[4][4];
#pragma unroll
  for (int m = 0; m < 4; ++m)
#pragma unroll
    for (int r = 0; r < 4; ++r) s[m][r] = 0.f;
#pragma unroll
  for (int m = 0; m < 4; ++m)
#pragma unroll
    for (int n = 0; n < 4; ++n)
#pragma unroll
      for (int r = 0; r < 4; ++r) {
        float v = fmaxf(acc[m][n][r] + b3v[n], 0.f);
        s[m][r] += v * w4v[n];
      }
#pragma unroll
  for (int m = 0; m < 4; ++m)
#pragma unroll
    for (int r = 0; r < 4; ++r) {
      float v = s[m][r];
      v += __shfl_xor(v, 1);
      v += __shfl_xor(v, 2);
      v += __shfl_xor(v, 4);
      v += __shfl_xor(v, 8);
      s[m][r] = v;
    }
  if (c15 == 0) {
#pragma unroll
    for (int m = 0; m < 4; ++m)
#pragma unroll
      for (int r = 0; r < 4; ++r) {
        int row = m0 + wr * 64 + m * 16 + j4 * 4 + r;
        out[(size_t)row * P_DIM + p] = s[m][r] + b4v;
      }
  }
}

extern "C" void kernel_launch(void* const* d_in, const int* in_sizes, int n_in,
                              void* d_out, int out_size, void* d_ws, size_t ws_size,
                              hipStream_t stream) {
  const float* x  = (const float*)d_in[0];
  const float* W1 = (const float*)d_in[1];
  const float* b1 = (const float*)d_in[2];
  const float* W2 = (const float*)d_in[3];
  const float* b2 = (const float*)d_in[4];
  const float* W3 = (const float*)d_in[5];
  const float* b3 = (const float*)d_in[6];
  const float* W4 = (const float*)d_in[7];
  const float* b4 = (const float*)d_in[8];
  float* out = (float*)d_out;

  char* ws = (char*)d_ws;
  u16*   W1f  = (u16*)(ws);                    // 20,480,000 B (fragment-linear)
  u16*   W2b  = (u16*)(ws + 20480000);         //    262,144 B
  u16*   W3T  = (u16*)(ws + 20742144);         //  4,194,304 B
  u16*   h1b  = (u16*)(ws + 24936448);         //  8,388,608 B
  u16*   h2b  = (u16*)(ws + 33325056);         //  4,194,304 B
  float* part = (float*)(ws + 37519360);       // 8 x 16 MB = 134,217,728 B (end ~172 MB)

  k_convert_w1frag<<<dim3((1280000 + 255) / 256), dim3(256), 0, stream>>>(W1, W1f);
  k_convert<<<dim3(131072 / 4 / 256), dim3(256), 0, stream>>>(W2, W2b, 131072 / 4);
  k_transpose_w3<<<dim3(2097152 / 256), dim3(256), 0, stream>>>(W3, W3T);

  k_gemm1<<<dim3(128 * SPLITK), dim3(512), 0, stream>>>(x, W1f, part);
  k_reduce1<<<dim3(B_DIM * H1_DIM / 4 / 256), dim3(256), 0, stream>>>(part, b1, h1b);
  k_gemm2<<<dim3(64, 4), dim3(256), 0, stream>>>(h1b, W2b, b2, h2b);
  k_heads<<<dim3(64, 64), dim3(256), 0, stream>>>(h2b, W3T, b3, W4, b4, out);
}